// Round 1
// baseline (60.513 us; speedup 1.0000x reference)
//
#include <hip/hip_runtime.h>
#include <hip/hip_bf16.h>

typedef __attribute__((ext_vector_type(8))) short s16x8;
typedef __attribute__((ext_vector_type(4))) float f32x4;

#define B_  8
#define N_  2048
#define F_  128
#define BM  64
#define BK  64

__device__ __forceinline__ short bfc(float f) {
  __hip_bfloat16 h = __float2bfloat16(f);   // RNE
  return __builtin_bit_cast(short, h);
}

// ---------------- kernel 1: degree -> dinv = (rowsum + 1)^-1/2 ----------------
__global__ __launch_bounds__(256) void k_deg(const float* __restrict__ adj,
                                             float* __restrict__ dinv) {
  const int row  = blockIdx.x * 4 + (threadIdx.x >> 6);
  const int lane = threadIdx.x & 63;
  const float* p = adj + (size_t)row * N_;
  float s = 0.f;
#pragma unroll
  for (int it = 0; it < 8; ++it) {
    float4 v = *reinterpret_cast<const float4*>(p + it * 256 + lane * 4);
    s += (v.x + v.y) + (v.z + v.w);
  }
#pragma unroll
  for (int off = 32; off > 0; off >>= 1) s += __shfl_down(s, off);
  if (lane == 0) dinv[row] = 1.0f / sqrtf(s + 1.0f);
}

// ---------------- kernel 2: fused normalize+aggregate+linear ----------------
// out[b,n,o] = sum_f ( d_n*(sum_m adj[b,n,m]*d_m*x[b,m,f]) + d_n^2*x[b,n,f] ) * W[o,f] + bias[o]
__global__ __launch_bounds__(512) void k_gcn(const float* __restrict__ adj,
                                             const float* __restrict__ x,
                                             const float* __restrict__ W,
                                             const float* __restrict__ bias,
                                             const float* __restrict__ dinv,
                                             float* __restrict__ out) {
  // LDS: main-loop tiles (aliased by out1 in epilogue) + resident W tile
  __shared__ short s_mem[BM * 72 + F_ * 72];  // 27648 B
  __shared__ short s_w[F_ * 136];             // 34816 B
  short* const s_adj = s_mem;                 // [BM][72]  row-major, +8 pad
  short* const s_xb  = s_mem + BM * 72;       // [F_][72]  (f,k) at f*72 + (k ^ (((f>>3)&7)<<3))
  short* const s_o1  = s_mem;                 // [BM][136] epilogue alias

  const int tid  = threadIdx.x;
  const int lane = tid & 63;
  const int wv   = tid >> 6;
  const int wrow = wv & 3;   // row-tile of 16 within BM=64
  const int whal = wv >> 2;  // column half of 64 within 128

  const int batch = blockIdx.x & 7;          // batch == XCD id -> x stays L2-resident
  const int n0    = (blockIdx.x >> 3) * BM;

  // ---- stage W (bf16) once: W_lds[o][f], +8 pad ----
  {
    const int o  = tid >> 2;
    const int f0 = (tid & 3) * 32;
    const float* wp = W + o * F_ + f0;
#pragma unroll
    for (int u = 0; u < 8; ++u) {
      float4 v = *reinterpret_cast<const float4*>(wp + u * 4);
      short4 h;
      h.x = bfc(v.x); h.y = bfc(v.y); h.z = bfc(v.z); h.w = bfc(v.w);
      *reinterpret_cast<short4*>(&s_w[o * 136 + f0 + u * 4]) = h;
    }
  }

  // ---- main loop: acc = adj_tile @ (d_m * x) ----
  const int ai  = tid >> 3;          // adj tile row 0..63
  const int aj  = (tid & 7) * 8;     // adj tile col base
  const int xk2 = tid >> 4;          // k-pair index 0..31
  const int xf0 = (tid & 15) * 8;    // feature base

  const float* adj_row = adj + (size_t)(batch * N_ + n0 + ai) * N_;
  const float* x_b     = x + (size_t)batch * N_ * F_;
  const float* dv_b    = dinv + batch * N_;

  float4 ra0, ra1, rx0, rx1, rx2, rx3;
  float rd0, rd1;

  auto issue = [&](int k0) {
    ra0 = *reinterpret_cast<const float4*>(adj_row + k0 + aj);
    ra1 = *reinterpret_cast<const float4*>(adj_row + k0 + aj + 4);
    const float* xr = x_b + (size_t)(k0 + 2 * xk2) * F_ + xf0;
    rx0 = *reinterpret_cast<const float4*>(xr);
    rx1 = *reinterpret_cast<const float4*>(xr + 4);
    rx2 = *reinterpret_cast<const float4*>(xr + F_);
    rx3 = *reinterpret_cast<const float4*>(xr + F_ + 4);
    rd0 = dv_b[k0 + 2 * xk2];
    rd1 = dv_b[k0 + 2 * xk2 + 1];
  };

  f32x4 acc[4] = {};

  issue(0);
#pragma unroll 1
  for (int t = 0; t < N_ / BK; ++t) {
    __syncthreads();  // previous compute done reading LDS
    // stage adj tile (f32 -> bf16)
    {
      s16x8 h;
      h[0] = bfc(ra0.x); h[1] = bfc(ra0.y); h[2] = bfc(ra0.z); h[3] = bfc(ra0.w);
      h[4] = bfc(ra1.x); h[5] = bfc(ra1.y); h[6] = bfc(ra1.z); h[7] = bfc(ra1.w);
      *reinterpret_cast<s16x8*>(&s_adj[ai * 72 + aj]) = h;
    }
    // stage x tile transposed + scaled by d_m, k-pair packed, XOR-swizzled
    {
      float a0[8] = {rx0.x, rx0.y, rx0.z, rx0.w, rx1.x, rx1.y, rx1.z, rx1.w};
      float a1[8] = {rx2.x, rx2.y, rx2.z, rx2.w, rx3.x, rx3.y, rx3.z, rx3.w};
      const int kbase = (2 * xk2) ^ ((tid & 7) << 3);  // (f>>3)&7 == tid&7 for all 8 f's
#pragma unroll
      for (int u = 0; u < 8; ++u) {
        unsigned lo = (unsigned short)bfc(a0[u] * rd0);
        unsigned hi = (unsigned short)bfc(a1[u] * rd1);
        *reinterpret_cast<unsigned*>(&s_xb[(xf0 + u) * 72 + kbase]) = lo | (hi << 16);
      }
    }
    if (t + 1 < N_ / BK) issue((t + 1) * BK);  // prefetch next tile across compute
    __syncthreads();
    // compute: 8 MFMA / wave / K-step
    {
      const int arow = (wrow * 16 + (lane & 15)) * 72 + ((lane >> 4) * 8);
      s16x8 a0 = *reinterpret_cast<const s16x8*>(&s_adj[arow]);
      s16x8 a1 = *reinterpret_cast<const s16x8*>(&s_adj[arow + 32]);
      const int krun = (lane >> 4) * 8;
#pragma unroll
      for (int ct = 0; ct < 4; ++ct) {
        const int f   = whal * 64 + ct * 16 + (lane & 15);
        const int xsw = ((f >> 3) & 7) << 3;
        s16x8 b0 = *reinterpret_cast<const s16x8*>(&s_xb[f * 72 + (krun ^ xsw)]);
        s16x8 b1 = *reinterpret_cast<const s16x8*>(&s_xb[f * 72 + ((krun + 32) ^ xsw)]);
        acc[ct] = __builtin_amdgcn_mfma_f32_16x16x32_bf16(a0, b0, acc[ct], 0, 0, 0);
        acc[ct] = __builtin_amdgcn_mfma_f32_16x16x32_bf16(a1, b1, acc[ct], 0, 0, 0);
      }
    }
  }

  // ---- epilogue: out1 = d_n*acc + d_n^2*x[n,f]  -> bf16 LDS -> @ W^T + bias ----
  __syncthreads();  // all waves done with s_adj/s_xb; safe to alias as s_o1
  {
    const int lr4 = (lane >> 4) * 4;
    const int lc  = lane & 15;
#pragma unroll
    for (int r = 0; r < 4; ++r) {
      const int nl = wrow * 16 + lr4 + r;          // C/D layout: row=(lane>>4)*4+reg
      const float dn = dv_b[n0 + nl];
      const float* xrow = x_b + (size_t)(n0 + nl) * F_;
#pragma unroll
      for (int ct = 0; ct < 4; ++ct) {
        const int f = whal * 64 + ct * 16 + lc;    // col = lane&15
        const float val = dn * acc[ct][r] + dn * dn * xrow[f];
        s_o1[nl * 136 + f] = bfc(val);
      }
    }
  }
  __syncthreads();

  f32x4 acc2[4] = {};
  {
    const int lc   = lane & 15;
    const int krun = (lane >> 4) * 8;
#pragma unroll
    for (int kk = 0; kk < 4; ++kk) {
      s16x8 af = *reinterpret_cast<const s16x8*>(
          &s_o1[(wrow * 16 + lc) * 136 + kk * 32 + krun]);
#pragma unroll
      for (int ot = 0; ot < 4; ++ot) {
        const int o = whal * 64 + ot * 16 + lc;
        s16x8 bf8 = *reinterpret_cast<const s16x8*>(&s_w[o * 136 + kk * 32 + krun]);
        acc2[ot] = __builtin_amdgcn_mfma_f32_16x16x32_bf16(af, bf8, acc2[ot], 0, 0, 0);
      }
    }
  }
  {
    const int lr4 = (lane >> 4) * 4;
    const int lc  = lane & 15;
#pragma unroll
    for (int ot = 0; ot < 4; ++ot) {
      const int o  = whal * 64 + ot * 16 + lc;
      const float bb = bias[o];
#pragma unroll
      for (int r = 0; r < 4; ++r) {
        const int nl = wrow * 16 + lr4 + r;
        out[(size_t)(batch * N_ + n0 + nl) * F_ + o] = acc2[ot][r] + bb;
      }
    }
  }
}

extern "C" void kernel_launch(void* const* d_in, const int* in_sizes, int n_in,
                              void* d_out, int out_size, void* d_ws, size_t ws_size,
                              hipStream_t stream) {
  const float* x   = (const float*)d_in[0];
  const float* adj = (const float*)d_in[1];
  const float* W   = (const float*)d_in[2];
  const float* b   = (const float*)d_in[3];
  float* outp  = (float*)d_out;
  float* dinv  = (float*)d_ws;  // 16384 floats = 64 KB

  k_deg<<<(B_ * N_) / 4, 256, 0, stream>>>(adj, dinv);
  k_gcn<<<B_ * (N_ / BM), 512, 0, stream>>>(adj, x, W, b, dinv, outp);
}

// Round 2
// 58.240 us; speedup vs baseline: 1.0390x; 1.0390x over previous
//
#include <hip/hip_runtime.h>
#include <hip/hip_bf16.h>

typedef __attribute__((ext_vector_type(8))) short s16x8;
typedef __attribute__((ext_vector_type(4))) float f32x4;

#define B_  8
#define N_  2048
#define F_  128
#define BM  32
#define BK  64
#define NT  (N_/BK)

__device__ __forceinline__ short bfc(float f) {
  __hip_bfloat16 h = __float2bfloat16(f);   // RNE
  return __builtin_bit_cast(short, h);
}

__device__ __forceinline__ void gload16(const void* g, void* l) {
  __builtin_amdgcn_global_load_lds(
      (const __attribute__((address_space(1))) unsigned*)g,
      (__attribute__((address_space(3))) unsigned*)l, 16, 0, 0);
}

// ---------------- kernel 1: degree -> dinv = (rowsum + 1)^-1/2 ----------------
__global__ __launch_bounds__(256) void k_deg(const float* __restrict__ adj,
                                             float* __restrict__ dinv) {
  const int row  = blockIdx.x * 4 + (threadIdx.x >> 6);
  const int lane = threadIdx.x & 63;
  const float* p = adj + (size_t)row * N_;
  float s = 0.f;
#pragma unroll
  for (int it = 0; it < 8; ++it) {
    float4 v = *reinterpret_cast<const float4*>(p + it * 256 + lane * 4);
    s += (v.x + v.y) + (v.z + v.w);
  }
#pragma unroll
  for (int off = 32; off > 0; off >>= 1) s += __shfl_down(s, off);
  if (lane == 0) dinv[row] = 1.0f / sqrtf(s + 1.0f);
}

// ---------------- kernel 2: xt[b][t][f][k_swz] = bf16(d_m * x[b, t*64+k, f]) ----------------
// tile-contiguous [128][64] bf16, element (f,k) at f*64 + (k ^ ((f&7)<<3))
__global__ __launch_bounds__(256) void k_prep(const float* __restrict__ x,
                                              const float* __restrict__ dinv,
                                              unsigned short* __restrict__ xt) {
  __shared__ short s[F_ * 64];
  const int b  = blockIdx.x >> 5;
  const int t  = blockIdx.x & 31;
  const int rp = threadIdx.x >> 3;          // row-pair 0..31
  const int f0 = (threadIdx.x & 7) * 16;
  const int r0 = rp * 2;
  const float* x0 = x + ((size_t)(b * N_) + t * 64 + r0) * F_ + f0;
  const float d0 = dinv[b * N_ + t * 64 + r0];
  const float d1 = dinv[b * N_ + t * 64 + r0 + 1];
#pragma unroll
  for (int u = 0; u < 16; u += 4) {
    float4 v0 = *reinterpret_cast<const float4*>(x0 + u);
    float4 v1 = *reinterpret_cast<const float4*>(x0 + F_ + u);
    float a0[4] = {v0.x, v0.y, v0.z, v0.w};
    float a1[4] = {v1.x, v1.y, v1.z, v1.w};
#pragma unroll
    for (int j = 0; j < 4; ++j) {
      const int f = f0 + u + j;
      unsigned lo = (unsigned short)bfc(a0[j] * d0);
      unsigned hi = (unsigned short)bfc(a1[j] * d1);
      *reinterpret_cast<unsigned*>(&s[f * 64 + (r0 ^ ((f & 7) << 3))]) = lo | (hi << 16);
    }
  }
  __syncthreads();
  const s16x8* sp = reinterpret_cast<const s16x8*>(s);
  s16x8* op = reinterpret_cast<s16x8*>(xt + (size_t)blockIdx.x * 8192);
#pragma unroll
  for (int j = 0; j < 4; ++j) op[threadIdx.x * 4 + j] = sp[threadIdx.x * 4 + j];
}

// ---------------- kernel 3: fused aggregate + linear ----------------
__global__ __launch_bounds__(512, 4) void k_gcn(const float* __restrict__ adj,
                                                const float* __restrict__ x,
                                                const float* __restrict__ W,
                                                const float* __restrict__ bias,
                                                const float* __restrict__ dinv,
                                                const unsigned short* __restrict__ xt,
                                                float* __restrict__ out) {
  __shared__ short s_main[2 * BM * 64 + 2 * F_ * 64];  // 40960 B
  __shared__ short s_w[F_ * 136];                      // 34816 B
  short* const sadj0 = s_main;                 // [32][64] swizzled
  short* const sadj1 = s_main + 2048;
  short* const sxt0  = s_main + 4096;          // [128][64] swizzled
  short* const sxt1  = s_main + 12288;
  short* const s_o1  = s_main;                 // [32][136] epilogue alias

  const int tid  = threadIdx.x;
  const int lane = tid & 63;
  const int wv   = tid >> 6;
  const int wrow = wv & 1;    // 2 x 16 rows
  const int wcol = wv >> 1;   // 4 x 32 cols of F

  const int batch = blockIdx.x & 7;            // batch pinned per XCD
  const int n0    = (blockIdx.x >> 3) * BM;

  // ---- stage W (bf16) once: s_w[o][f], pad to 136 ----
  {
    const int o   = tid >> 2;
    const int f0c = (tid & 3) * 32;
    const float* wp = W + o * F_ + f0c;
#pragma unroll
    for (int u = 0; u < 8; ++u) {
      float4 v = *reinterpret_cast<const float4*>(wp + u * 4);
      short4 h;
      h.x = bfc(v.x); h.y = bfc(v.y); h.z = bfc(v.z); h.w = bfc(v.w);
      *reinterpret_cast<short4*>(&s_w[o * 136 + f0c + u * 4]) = h;
    }
  }
  // drain W loads so they can't pollute the counted vmcnt discipline below
  asm volatile("s_waitcnt vmcnt(0)" ::: "memory");
  __builtin_amdgcn_sched_barrier(0);

  // adj staging: thread owns row ai, 4 cols at aj
  const int ai = tid >> 4;
  const int aj = (tid & 15) * 4;
  const float* adj_row = adj + (size_t)(batch * N_ + n0 + ai) * N_ + aj;
  const int a_lds = ai * 64 + (aj ^ ((ai & 7) << 3));

  const unsigned short* xt_b = xt + (size_t)batch * NT * 8192;

  f32x4 acc[2] = {};
  float4 aA, aB;

  // prologue: issue order [A0, X0 x2, A1]
  aA = *reinterpret_cast<const float4*>(adj_row);
  gload16(xt_b + tid * 8, sxt0 + tid * 8);
  gload16(xt_b + 4096 + tid * 8, sxt0 + 4096 + tid * 8);
  aB = *reinterpret_cast<const float4*>(adj_row + BK);

  auto step = [&](int t, float4& aCur, short* sadj_c, short* sxt_c, short* sxt_n) {
    // stage adj tile t (compiler auto-waits aCur, leaving newer X/A in flight)
    {
      short4 h;
      h.x = bfc(aCur.x); h.y = bfc(aCur.y); h.z = bfc(aCur.z); h.w = bfc(aCur.w);
      *reinterpret_cast<short4*>(&sadj_c[a_lds]) = h;
    }
    // X_t arrived (leave A_{t+1} in flight); own LDS writes done
    if (t < NT - 1) asm volatile("s_waitcnt vmcnt(1) lgkmcnt(0)" ::: "memory");
    else            asm volatile("s_waitcnt vmcnt(0) lgkmcnt(0)" ::: "memory");
    __builtin_amdgcn_s_barrier();
    __builtin_amdgcn_sched_barrier(0);
    // post-barrier issues (safe: barrier proves compute t-1 done with sxt_n)
    if (t + 1 < NT) {
      const unsigned short* src = xt_b + (size_t)(t + 1) * 8192;
      gload16(src + tid * 8, sxt_n + tid * 8);
      gload16(src + 4096 + tid * 8, sxt_n + 4096 + tid * 8);
      if (t + 2 < NT) aCur = *reinterpret_cast<const float4*>(adj_row + (t + 2) * BK);
    }
    // compute: 4 MFMA / wave
    {
      const int row  = wrow * 16 + (lane & 15);
      const int swzr = (row & 7) << 3;
      const int krun = (lane >> 4) * 8;
      const short* sa = sadj_c + row * 64;
      s16x8 a0 = *reinterpret_cast<const s16x8*>(sa + (krun ^ swzr));
      s16x8 a1 = *reinterpret_cast<const s16x8*>(sa + ((32 + krun) ^ swzr));
#pragma unroll
      for (int ct = 0; ct < 2; ++ct) {
        const int f    = wcol * 32 + ct * 16 + (lane & 15);
        const int swzf = (f & 7) << 3;
        const short* sb = sxt_c + f * 64;
        s16x8 b0 = *reinterpret_cast<const s16x8*>(sb + (krun ^ swzf));
        s16x8 b1 = *reinterpret_cast<const s16x8*>(sb + ((32 + krun) ^ swzf));
        acc[ct] = __builtin_amdgcn_mfma_f32_16x16x32_bf16(a0, b0, acc[ct], 0, 0, 0);
        acc[ct] = __builtin_amdgcn_mfma_f32_16x16x32_bf16(a1, b1, acc[ct], 0, 0, 0);
      }
    }
  };

#pragma unroll 1
  for (int tt = 0; tt < NT; tt += 2) {
    step(tt,     aA, sadj0, sxt0, sxt1);
    step(tt + 1, aB, sadj1, sxt1, sxt0);
  }

  // ---- epilogue ----
  __syncthreads();
  {
    const int lr4 = (lane >> 4) * 4;
    const int lc  = lane & 15;
#pragma unroll
    for (int r = 0; r < 4; ++r) {
      const int nl = wrow * 16 + lr4 + r;
      const float dn = dinv[batch * N_ + n0 + nl];
      const float* xrow = x + (size_t)(batch * N_ + n0 + nl) * F_;
#pragma unroll
      for (int ct = 0; ct < 2; ++ct) {
        const int f = wcol * 32 + ct * 16 + lc;
        s_o1[nl * 136 + f] = bfc(dn * acc[ct][r] + dn * dn * xrow[f]);
      }
    }
  }
  __syncthreads();

  f32x4 acc2[2] = {};
  {
    const int lc   = lane & 15;
    const int krun = (lane >> 4) * 8;
#pragma unroll
    for (int kk = 0; kk < 4; ++kk) {
      s16x8 af = *reinterpret_cast<const s16x8*>(&s_o1[(wrow * 16 + lc) * 136 + kk * 32 + krun]);
#pragma unroll
      for (int ot = 0; ot < 2; ++ot) {
        const int o = wcol * 32 + ot * 16 + lc;
        s16x8 bw = *reinterpret_cast<const s16x8*>(&s_w[o * 136 + kk * 32 + krun]);
        acc2[ot] = __builtin_amdgcn_mfma_f32_16x16x32_bf16(af, bw, acc2[ot], 0, 0, 0);
      }
    }
  }
  {
    const int lr4 = (lane >> 4) * 4;
    const int lc  = lane & 15;
#pragma unroll
    for (int ot = 0; ot < 2; ++ot) {
      const int o  = wcol * 32 + ot * 16 + lc;
      const float bb = bias[o];
#pragma unroll
      for (int r = 0; r < 4; ++r) {
        const int nl = wrow * 16 + lr4 + r;
        out[(size_t)(batch * N_ + n0 + nl) * F_ + o] = acc2[ot][r] + bb;
      }
    }
  }
}

// ---------------- fallback (round-1 kernel) if ws too small ----------------
__global__ __launch_bounds__(512) void k_gcn_fb(const float* __restrict__ adj,
                                                const float* __restrict__ x,
                                                const float* __restrict__ W,
                                                const float* __restrict__ bias,
                                                const float* __restrict__ dinv,
                                                float* __restrict__ out) {
  __shared__ short s_mem[64 * 72 + F_ * 72];
  __shared__ short s_w[F_ * 136];
  short* const s_adj = s_mem;
  short* const s_xb  = s_mem + 64 * 72;
  short* const s_o1  = s_mem;

  const int tid  = threadIdx.x;
  const int lane = tid & 63;
  const int wv   = tid >> 6;
  const int wrow = wv & 3;
  const int whal = wv >> 2;

  const int batch = blockIdx.x & 7;
  const int n0    = (blockIdx.x >> 3) * 64;

  {
    const int o  = tid >> 2;
    const int f0 = (tid & 3) * 32;
    const float* wp = W + o * F_ + f0;
#pragma unroll
    for (int u = 0; u < 8; ++u) {
      float4 v = *reinterpret_cast<const float4*>(wp + u * 4);
      short4 h;
      h.x = bfc(v.x); h.y = bfc(v.y); h.z = bfc(v.z); h.w = bfc(v.w);
      *reinterpret_cast<short4*>(&s_w[o * 136 + f0 + u * 4]) = h;
    }
  }

  const int ai  = tid >> 3;
  const int aj  = (tid & 7) * 8;
  const int xk2 = tid >> 4;
  const int xf0 = (tid & 15) * 8;

  const float* adj_row = adj + (size_t)(batch * N_ + n0 + ai) * N_;
  const float* x_b     = x + (size_t)batch * N_ * F_;
  const float* dv_b    = dinv + batch * N_;

  float4 ra0, ra1, rx0, rx1, rx2, rx3;
  float rd0, rd1;

  auto issue = [&](int k0) {
    ra0 = *reinterpret_cast<const float4*>(adj_row + k0 + aj);
    ra1 = *reinterpret_cast<const float4*>(adj_row + k0 + aj + 4);
    const float* xr = x_b + (size_t)(k0 + 2 * xk2) * F_ + xf0;
    rx0 = *reinterpret_cast<const float4*>(xr);
    rx1 = *reinterpret_cast<const float4*>(xr + 4);
    rx2 = *reinterpret_cast<const float4*>(xr + F_);
    rx3 = *reinterpret_cast<const float4*>(xr + F_ + 4);
    rd0 = dv_b[k0 + 2 * xk2];
    rd1 = dv_b[k0 + 2 * xk2 + 1];
  };

  f32x4 acc[4] = {};
  issue(0);
#pragma unroll 1
  for (int t = 0; t < N_ / 64; ++t) {
    __syncthreads();
    {
      s16x8 h;
      h[0] = bfc(ra0.x); h[1] = bfc(ra0.y); h[2] = bfc(ra0.z); h[3] = bfc(ra0.w);
      h[4] = bfc(ra1.x); h[5] = bfc(ra1.y); h[6] = bfc(ra1.z); h[7] = bfc(ra1.w);
      *reinterpret_cast<s16x8*>(&s_adj[ai * 72 + aj]) = h;
    }
    {
      float a0[8] = {rx0.x, rx0.y, rx0.z, rx0.w, rx1.x, rx1.y, rx1.z, rx1.w};
      float a1[8] = {rx2.x, rx2.y, rx2.z, rx2.w, rx3.x, rx3.y, rx3.z, rx3.w};
      const int kbase = (2 * xk2) ^ ((tid & 7) << 3);
#pragma unroll
      for (int u = 0; u < 8; ++u) {
        unsigned lo = (unsigned short)bfc(a0[u] * rd0);
        unsigned hi = (unsigned short)bfc(a1[u] * rd1);
        *reinterpret_cast<unsigned*>(&s_xb[(xf0 + u) * 72 + kbase]) = lo | (hi << 16);
      }
    }
    if (t + 1 < N_ / 64) issue((t + 1) * 64);
    __syncthreads();
    {
      const int arow = (wrow * 16 + (lane & 15)) * 72 + ((lane >> 4) * 8);
      s16x8 a0 = *reinterpret_cast<const s16x8*>(&s_adj[arow]);
      s16x8 a1 = *reinterpret_cast<const s16x8*>(&s_adj[arow + 32]);
      const int krun = (lane >> 4) * 8;
#pragma unroll
      for (int ct = 0; ct < 4; ++ct) {
        const int f   = whal * 64 + ct * 16 + (lane & 15);
        const int xsw = ((f >> 3) & 7) << 3;
        s16x8 b0 = *reinterpret_cast<const s16x8*>(&s_xb[f * 72 + (krun ^ xsw)]);
        s16x8 b1 = *reinterpret_cast<const s16x8*>(&s_xb[f * 72 + ((krun + 32) ^ xsw)]);
        acc[ct] = __builtin_amdgcn_mfma_f32_16x16x32_bf16(a0, b0, acc[ct], 0, 0, 0);
        acc[ct] = __builtin_amdgcn_mfma_f32_16x16x32_bf16(a1, b1, acc[ct], 0, 0, 0);
      }
    }
  }

  __syncthreads();
  {
    const int lr4 = (lane >> 4) * 4;
    const int lc  = lane & 15;
#pragma unroll
    for (int r = 0; r < 4; ++r) {
      const int nl = wrow * 16 + lr4 + r;
      const float dn = dv_b[n0 + nl];
      const float* xrow = x_b + (size_t)(n0 + nl) * F_;
#pragma unroll
      for (int ct = 0; ct < 4; ++ct) {
        const int f = whal * 64 + ct * 16 + lc;
        s_o1[nl * 136 + f] = bfc(dn * acc[ct][r] + dn * dn * xrow[f]);
      }
    }
  }
  __syncthreads();

  f32x4 acc2[4] = {};
  {
    const int lc   = lane & 15;
    const int krun = (lane >> 4) * 8;
#pragma unroll
    for (int kk = 0; kk < 4; ++kk) {
      s16x8 af = *reinterpret_cast<const s16x8*>(&s_o1[(wrow * 16 + lc) * 136 + kk * 32 + krun]);
#pragma unroll
      for (int ot = 0; ot < 4; ++ot) {
        const int o = whal * 64 + ot * 16 + lc;
        s16x8 bf8 = *reinterpret_cast<const s16x8*>(&s_w[o * 136 + kk * 32 + krun]);
        acc2[ot] = __builtin_amdgcn_mfma_f32_16x16x32_bf16(af, bf8, acc2[ot], 0, 0, 0);
      }
    }
  }
  {
    const int lr4 = (lane >> 4) * 4;
    const int lc  = lane & 15;
#pragma unroll
    for (int ot = 0; ot < 4; ++ot) {
      const int o  = whal * 64 + ot * 16 + lc;
      const float bb = bias[o];
#pragma unroll
      for (int r = 0; r < 4; ++r) {
        const int nl = wrow * 16 + lr4 + r;
        out[(size_t)(batch * N_ + n0 + nl) * F_ + o] = acc2[ot][r] + bb;
      }
    }
  }
}

extern "C" void kernel_launch(void* const* d_in, const int* in_sizes, int n_in,
                              void* d_out, int out_size, void* d_ws, size_t ws_size,
                              hipStream_t stream) {
  const float* x   = (const float*)d_in[0];
  const float* adj = (const float*)d_in[1];
  const float* W   = (const float*)d_in[2];
  const float* b   = (const float*)d_in[3];
  float* outp = (float*)d_out;
  float* dinv = (float*)d_ws;                                        // 64 KB
  unsigned short* xt = (unsigned short*)((char*)d_ws + 65536);       // 4 MB

  k_deg<<<(B_ * N_) / 4, 256, 0, stream>>>(adj, dinv);
  if (ws_size >= 65536 + (size_t)B_ * NT * 8192 * 2) {
    k_prep<<<B_ * NT, 256, 0, stream>>>(x, dinv, xt);
    k_gcn<<<B_ * (N_ / BM), 512, 0, stream>>>(adj, x, W, b, dinv, xt, outp);
  } else {
    k_gcn_fb<<<B_ * (N_ / 64), 512, 0, stream>>>(adj, x, W, b, dinv, outp);
  }
}